// Round 5
// baseline (218.561 us; speedup 1.0000x reference)
//
#include <hip/hip_runtime.h>

#define T 8192
#define NCH 128
#define NB 8
#define NS (NB * NCH)   // 1024 series
#define TM1 (T - 1)

typedef __bf16 v8bf __attribute__((ext_vector_type(8)));
typedef float v16f __attribute__((ext_vector_type(16)));

#define WREV_LEN 8448                 // per-copy per-series length (elems)
#define WREV_COPY_STRIDE ((size_t)NS * WREV_LEN)

// 16B vector load from a 4B-aligned address (gfx950 unaligned global access)
struct __attribute__((packed, aligned(4))) U16 { uint4 v; };
struct __attribute__((packed, aligned(4))) F16V { float4 v; };

__device__ __forceinline__ uint bf_bits(float f) {
  union { float f; uint u; } v; v.f = f;
  return (v.u + 0x7FFFu + ((v.u >> 16) & 1u)) >> 16;
}

__device__ __forceinline__ uint wbits(const float* wsh, int k) {
  if ((unsigned)k > 8191u) return 0u;
  return bf_bits(wsh[k + (k >> 5)]);
}

// ---------------- Kernel A: weights cumprod -> reversed bf16 (2 parity copies)
__global__ __launch_bounds__(256) void wkern(const float* __restrict__ alpha,
                                             ushort* __restrict__ wr2) {
  const int sid = blockIdx.x;
  const float a = fmaxf(alpha[sid], 0.f);
  const int j = threadIdx.x;
  __shared__ float sc[256];
  __shared__ float wsh[8448];          // idx k + (k>>5): stride-33, conflict-free
  const int k0 = j << 5;
  float c = 1.f;
  #pragma unroll
  for (int s = 1; s <= 32; ++s) {
    const float k = (float)(k0 + s);
    c *= (k - 1.f - a) / k;
  }
  sc[j] = c;
  __syncthreads();
  for (int off = 1; off < 256; off <<= 1) {
    const float u = (j >= off) ? sc[j - off] : 1.f;
    const float v = sc[j];
    __syncthreads();
    sc[j] = u * v;
    __syncthreads();
  }
  float p = (j == 0) ? 1.f : sc[j - 1];
  wsh[k0 + j] = p;
  for (int s = 1; s < 32; ++s) {
    const float k = (float)(k0 + s);
    p *= (k - 1.f - a) / k;
    wsh[k0 + s + j] = p;
  }
  __syncthreads();
  uint* c0u = (uint*)(wr2 + (size_t)sid * WREV_LEN);
  uint* c1u = (uint*)(wr2 + WREV_COPY_STRIDE + (size_t)sid * WREV_LEN);
  for (int d = j; d < WREV_LEN / 2; d += 256) {
    const int z = 2 * d;
    const uint a0 = wbits(wsh, 8319 - z);
    const uint a1 = wbits(wsh, 8318 - z);
    const uint a2 = wbits(wsh, 8317 - z);
    c0u[d] = a0 | (a1 << 16);
    c1u[d] = a1 | (a2 << 16);
  }
}

// ---------------- Kernel B: transpose X (B,T,n) fp32 -> xT (B*n, T) bf16 ---
__global__ __launch_bounds__(256) void tkern(const float* __restrict__ X,
                                             ushort* __restrict__ xT) {
  __shared__ float tile[32][33];
  const int b = blockIdx.z;
  const int i0 = blockIdx.y << 5;
  const int t0 = blockIdx.x << 5;
  const int tx = threadIdx.x;
  const int ty = threadIdx.y;
  #pragma unroll
  for (int k = 0; k < 4; ++k) {
    const int t = t0 + ty + (k << 3);
    tile[ty + (k << 3)][tx] = X[((size_t)b * T + t) * NCH + i0 + tx];
  }
  __syncthreads();
  #pragma unroll
  for (int k = 0; k < 4; ++k) {
    const int i = i0 + ty + (k << 3);
    xT[((size_t)(b * NCH + i)) * T + t0 + tx] =
        (ushort)bf_bits(tile[tx][ty + (k << 3)]);
  }
}

// ---------------- Kernel C: causal Toeplitz filter via MFMA -----------------
// Work split per wave: (cc-half, K-parity). cch=0 -> cc {0,3}, cch=1 -> {1,2}
// (648 MFMA-pairs each, balanced). acc = 64 AGPR -> 3 blocks/CU.
__global__ __launch_bounds__(256, 3) void convk(const ushort* __restrict__ wr2,
                                                const ushort* __restrict__ xT,
                                                float* __restrict__ yT) {
  const int sid = blockIdx.x;
  const int tid = threadIdx.x;
  const int wave = tid >> 6;
  const int lane = tid & 63;
  const int ln31 = lane & 31;
  const int q = lane >> 5;

  __shared__ uint4 arena16[1280];      // 20 KB; x-stage (main) / reduce zones

  // zero left pad: chunks u in [0,256)
  {
    const int u = tid;
    arena16[((u & 7) * 160) + (u >> 3)] = make_uint4(0, 0, 0, 0);
  }
  // stage x: data chunk u = 256 + u0, u0 in [0,1024)
  {
    const uint4* xg16 = (const uint4*)(xT + (size_t)sid * T);
    for (int u0 = tid; u0 < 1024; u0 += 256) {
      const int u = u0 + 256;
      arena16[((u & 7) * 160) + (u >> 3)] = xg16[u0];
    }
  }
  __syncthreads();

  const int Kpar = wave & 1;
  const int cch = wave >> 1;
  const int ccA = cch ? 1 : 0;
  const int ccB = cch ? 2 : 3;
  const int limA = 128 * (ccA + 1);
  const int limB = 128 * (ccB + 1);
  const int offA = 32 * ccA;
  const int offB = 32 * ccB;

  v16f acc[2][2];
  #pragma unroll
  for (int ci = 0; ci < 2; ++ci)
    #pragma unroll
    for (int rt = 0; rt < 2; ++rt)
      #pragma unroll
      for (int e = 0; e < 16; ++e) acc[ci][rt][e] = 0.f;

  const int s0_par = (8303 - ln31 + 8 * q) & 1;
  const uint* wu = (const uint*)(wr2 + (s0_par ? WREV_COPY_STRIDE : 0) +
                                 (size_t)sid * WREV_LEN);

  for (int K = Kpar; K < 65; K += 2) {
    const int ibase = -4 + K * 8;
    const int s0 = 8303 - 16 * ibase - ln31 + 8 * q;
    const int dw0 = (s0 - s0_par) >> 1;
    uint4 av[10];
    #pragma unroll
    for (int j2 = 0; j2 < 10; ++j2)
      av[j2] = ((const U16*)(wu + (dw0 - 8 * j2)))->v;
    #pragma unroll
    for (int ii = 0; ii < 8; ++ii) {
      const int i = ibase + ii;
      const v8bf A0 = __builtin_bit_cast(v8bf, av[ii]);
      const v8bf A1 = __builtin_bit_cast(v8bf, av[ii + 2]);   // dw-16 reuse
      const int m2 = -2 * (i + 1);
      const int u70 = m2 & 7;
      const int u71 = (m2 + 1) & 7;
      const int G0 = u70 * 160 + 32 + ((m2 - u70) >> 3);
      const int G1 = u71 * 160 + 32 + ((m2 + 1 - u71) >> 3);
      const int phi = ln31 + (q ? G1 : G0);
      if (i < limA) {
        const uint4 bv = arena16[phi + offA];
        const v8bf Bf = __builtin_bit_cast(v8bf, bv);
        acc[0][0] = __builtin_amdgcn_mfma_f32_32x32x16_bf16(A0, Bf, acc[0][0], 0, 0, 0);
        acc[0][1] = __builtin_amdgcn_mfma_f32_32x32x16_bf16(A1, Bf, acc[0][1], 0, 0, 0);
      }
      if (i < limB) {
        const uint4 bv = arena16[phi + offB];
        const v8bf Bf = __builtin_bit_cast(v8bf, bv);
        acc[1][0] = __builtin_amdgcn_mfma_f32_32x32x16_bf16(A0, Bf, acc[1][0], 0, 0, 0);
        acc[1][1] = __builtin_amdgcn_mfma_f32_32x32x16_bf16(A1, Bf, acc[1][1], 0, 0, 0);
      }
    }
  }

  // ---- cross-wave reduction: tile (cc,rt) partials live in waves 2cch+{0,1}
  float* const zbase = (float*)arena16;
  #pragma unroll
  for (int rep = 0; rep < 4; ++rep) {
    const int ci = rep >> 1;
    const int rt = rep & 1;
    __syncthreads();
    {
      float* zone = zbase + wave * 1152 + ln31 * 36 + 4 * q;
      #pragma unroll
      for (int g = 0; g < 4; ++g) {
        *(float4*)(zone + 8 * g) = make_float4(acc[ci][rt][4 * g],
                                               acc[ci][rt][4 * g + 1],
                                               acc[ci][rt][4 * g + 2],
                                               acc[ci][rt][4 * g + 3]);
      }
    }
    __syncthreads();
    const int tsel = tid >> 7;          // which cch pair
    const int n2 = tid & 31;
    const int rr = (tid >> 5) & 3;      // row group of 8
    const int cc = tsel ? (ci ? 2 : 1) : (ci ? 3 : 0);
    const float* za = zbase + (tsel ? 2304 : 0) + n2 * 36 + 8 * rr;
    const float* zb = za + 1152;
    float* yo = yT + (size_t)sid * T + 2048 * cc + 64 * n2 + 32 * rt + 8 * rr;
    #pragma unroll
    for (int h = 0; h < 2; ++h) {
      const float4 sa = *(const float4*)(za + 4 * h);
      const float4 sb = *(const float4*)(zb + 4 * h);
      *(float4*)(yo + 4 * h) = make_float4(sa.x + sb.x, sa.y + sb.y,
                                           sa.z + sb.z, sa.w + sb.w);
    }
  }
}

// ---------------- Kernel D: out = Y[:,1:,:] - X[:,:-1,:] @ A^T  (MFMA) ------
// 64 t x 128 j per block. Epilogue: yT tile staged into LDS [t][j] stride-133
// via coalesced row reads, then conflict-free scalar LDS reads.
__global__ __launch_bounds__(256) void outk(const float* __restrict__ X,
                                            const float* __restrict__ A,
                                            const float* __restrict__ yT,
                                            float* __restrict__ out) {
  const int b = blockIdx.y;
  const int t0 = blockIdx.x << 6;     // 64 t's per block
  const int tid = threadIdx.x;
  const int wave = tid >> 6;          // = n-tile
  const int lane = tid & 63;
  const int ln31 = lane & 31;
  const int q = lane >> 5;

  __shared__ uint4 arena[3072];       // 48KB: Amat 32KB + X 16KB, reused for yT

  // stage Amat bf16: chunk (j, c4) at phiA = c4*128 + ((j + c4) & 127)
  {
    const float* Ab = A + (size_t)b * NCH * NCH;
    #pragma unroll
    for (int g = 0; g < 8; ++g) {
      const int u = g * 256 + tid;
      const int jr = u >> 4, c4 = u & 15;
      const float4 f0 = *(const float4*)(Ab + jr * NCH + 8 * c4);
      const float4 f1 = *(const float4*)(Ab + jr * NCH + 8 * c4 + 4);
      uint4 pk;
      pk.x = bf_bits(f0.x) | (bf_bits(f0.y) << 16);
      pk.y = bf_bits(f0.z) | (bf_bits(f0.w) << 16);
      pk.z = bf_bits(f1.x) | (bf_bits(f1.y) << 16);
      pk.w = bf_bits(f1.z) | (bf_bits(f1.w) << 16);
      arena[c4 * 128 + ((jr + c4) & 127)] = pk;
    }
  }
  // stage X-tile bf16: chunk (m, c4) at 2048 + c4*64 + ((m + c4) & 63)
  {
    const float* Xb = X + ((size_t)b * T + t0) * NCH;
    #pragma unroll
    for (int g = 0; g < 4; ++g) {
      const int u = g * 256 + tid;
      const int m = u >> 4, c4 = u & 15;
      const float4 f0 = *(const float4*)(Xb + m * NCH + 8 * c4);
      const float4 f1 = *(const float4*)(Xb + m * NCH + 8 * c4 + 4);
      uint4 pk;
      pk.x = bf_bits(f0.x) | (bf_bits(f0.y) << 16);
      pk.y = bf_bits(f0.z) | (bf_bits(f0.w) << 16);
      pk.z = bf_bits(f1.x) | (bf_bits(f1.y) << 16);
      pk.w = bf_bits(f1.z) | (bf_bits(f1.w) << 16);
      arena[2048 + c4 * 64 + ((m + c4) & 63)] = pk;
    }
  }
  __syncthreads();

  v16f acc[2];
  #pragma unroll
  for (int mt = 0; mt < 2; ++mt)
    #pragma unroll
    for (int e = 0; e < 16; ++e) acc[mt][e] = 0.f;

  const int nt = wave;
  #pragma unroll
  for (int kk = 0; kk < 8; ++kk) {
    const int c4 = 2 * kk + q;
    const uint4 bv = arena[c4 * 128 + ((nt * 32 + ln31 + c4) & 127)];
    const v8bf Bf = __builtin_bit_cast(v8bf, bv);
    #pragma unroll
    for (int mt = 0; mt < 2; ++mt) {
      const uint4 avv = arena[2048 + c4 * 64 + ((mt * 32 + ln31 + c4) & 63)];
      const v8bf Af = __builtin_bit_cast(v8bf, avv);
      acc[mt] = __builtin_amdgcn_mfma_f32_32x32x16_bf16(Af, Bf, acc[mt], 0, 0, 0);
    }
  }

  __syncthreads();                     // Amat/X dead; reuse arena for yT tile
  // stage yT tile: yl[t][j] = yT[j][t0 + t + 1], rows stride 133 (2-way banks)
  float* const yl = (float*)arena;     // 64*133 = 8512 floats = 34KB
  {
    #pragma unroll
    for (int g = 0; g < 8; ++g) {
      const int u = g * 256 + tid;     // 0..2047
      const int jr = u >> 4, c = u & 15;
      const float* yg = yT + ((size_t)(b * NCH + jr)) * T + t0 + 4 * c + 1;
      const float4 v = ((const F16V*)yg)->v;
      yl[(4 * c + 0) * 133 + jr] = v.x;
      yl[(4 * c + 1) * 133 + jr] = v.y;
      yl[(4 * c + 2) * 133 + jr] = v.z;
      yl[(4 * c + 3) * 133 + jr] = v.w;
    }
  }
  __syncthreads();

  const int jj = nt * 32 + ln31;
  float* og = out + (size_t)b * TM1 * NCH + jj;
  #pragma unroll
  for (int mt = 0; mt < 2; ++mt) {
    #pragma unroll
    for (int g = 0; g < 4; ++g) {
      const int r0 = mt * 32 + 8 * g + 4 * q;          // rows r0..r0+3
      #pragma unroll
      for (int e = 0; e < 4; ++e) {
        const int t = t0 + r0 + e;
        const float val = yl[(r0 + e) * 133 + jj] - acc[mt][4 * g + e];
        if (t < TM1) og[(size_t)t * NCH] = val;
      }
    }
  }
}

extern "C" void kernel_launch(void* const* d_in, const int* in_sizes, int n_in,
                              void* d_out, int out_size, void* d_ws, size_t ws_size,
                              hipStream_t stream) {
  const float* X     = (const float*)d_in[0];   // (8, 8192, 128)
  const float* alpha = (const float*)d_in[1];   // (8, 128)
  const float* A     = (const float*)d_in[2];   // (8, 128, 128)
  float* out = (float*)d_out;                   // (8, 8191, 128)
  char* ws = (char*)d_ws;

  ushort* wr2 = (ushort*)ws;                         // 34,603,008 B
  ushort* xT  = (ushort*)(ws + 34603008);            // 16,777,216 B
  float*  yT  = (float*)(ws + 34603008 + 16777216);  // 33,554,432 B

  hipLaunchKernelGGL(wkern, dim3(NS), dim3(256), 0, stream, alpha, wr2);
  hipLaunchKernelGGL(tkern, dim3(T / 32, NCH / 32, NB), dim3(32, 8), 0, stream, X, xT);
  hipLaunchKernelGGL(convk, dim3(NS), dim3(256), 0, stream, wr2, xT, yT);
  hipLaunchKernelGGL(outk, dim3(T / 64, NB), dim3(256), 0, stream, X, A, yT, out);
}

// Round 6
// 204.567 us; speedup vs baseline: 1.0684x; 1.0684x over previous
//
#include <hip/hip_runtime.h>

#define T 8192
#define NCH 128
#define NB 8
#define NS (NB * NCH)   // 1024 series
#define TM1 (T - 1)

typedef __bf16 v8bf __attribute__((ext_vector_type(8)));
typedef float v16f __attribute__((ext_vector_type(16)));

#define WREV_LEN 8448                 // per-copy per-series length (elems)
#define WREV_COPY_STRIDE ((size_t)NS * WREV_LEN)

// x LDS pad: 2304 zero elems (supports phase-boundary overshoot to t=-2112)
#define XPAD 2304
#define NCHUNK ((XPAD + T) / 8)       // 1312 16B chunks
#define ROWL (NCHUNK / 8)             // 164 chunks per swizzle row

// 16B vector load from a 4B-aligned address (gfx950 unaligned global access)
struct __attribute__((packed, aligned(4))) U16 { uint4 v; };
struct __attribute__((packed, aligned(4))) F16V { float4 v; };

__device__ __forceinline__ uint bf_bits(float f) {
  union { float f; uint u; } v; v.f = f;
  return (v.u + 0x7FFFu + ((v.u >> 16) & 1u)) >> 16;
}

__device__ __forceinline__ uint wbits(const float* wsh, int k) {
  if ((unsigned)k > 8191u) return 0u;
  return bf_bits(wsh[k + (k >> 5)]);
}

// ---------------- Kernel A: weights cumprod -> reversed bf16 (2 parity copies)
__global__ __launch_bounds__(256) void wkern(const float* __restrict__ alpha,
                                             ushort* __restrict__ wr2) {
  const int sid = blockIdx.x;
  const float a = fmaxf(alpha[sid], 0.f);
  const int j = threadIdx.x;
  __shared__ float sc[256];
  __shared__ float wsh[8448];          // idx k + (k>>5): stride-33, conflict-free
  const int k0 = j << 5;
  float c = 1.f;
  #pragma unroll
  for (int s = 1; s <= 32; ++s) {
    const float k = (float)(k0 + s);
    c *= (k - 1.f - a) / k;
  }
  sc[j] = c;
  __syncthreads();
  for (int off = 1; off < 256; off <<= 1) {
    const float u = (j >= off) ? sc[j - off] : 1.f;
    const float v = sc[j];
    __syncthreads();
    sc[j] = u * v;
    __syncthreads();
  }
  float p = (j == 0) ? 1.f : sc[j - 1];
  wsh[k0 + j] = p;
  for (int s = 1; s < 32; ++s) {
    const float k = (float)(k0 + s);
    p *= (k - 1.f - a) / k;
    wsh[k0 + s + j] = p;
  }
  __syncthreads();
  uint* c0u = (uint*)(wr2 + (size_t)sid * WREV_LEN);
  uint* c1u = (uint*)(wr2 + WREV_COPY_STRIDE + (size_t)sid * WREV_LEN);
  for (int d = j; d < WREV_LEN / 2; d += 256) {
    const int z = 2 * d;
    const uint a0 = wbits(wsh, 8319 - z);
    const uint a1 = wbits(wsh, 8318 - z);
    const uint a2 = wbits(wsh, 8317 - z);
    c0u[d] = a0 | (a1 << 16);
    c1u[d] = a1 | (a2 << 16);
  }
}

// ---------------- Kernel B: transpose X (B,T,n) fp32 -> xT (B*n, T) bf16 ---
__global__ __launch_bounds__(256) void tkern(const float* __restrict__ X,
                                             ushort* __restrict__ xT) {
  __shared__ float tile[32][33];
  const int b = blockIdx.z;
  const int i0 = blockIdx.y << 5;
  const int t0 = blockIdx.x << 5;
  const int tx = threadIdx.x;
  const int ty = threadIdx.y;
  #pragma unroll
  for (int k = 0; k < 4; ++k) {
    const int t = t0 + ty + (k << 3);
    tile[ty + (k << 3)][tx] = X[((size_t)b * T + t) * NCH + i0 + tx];
  }
  __syncthreads();
  #pragma unroll
  for (int k = 0; k < 4; ++k) {
    const int i = i0 + ty + (k << 3);
    xT[((size_t)(b * NCH + i)) * T + t0 + tx] =
        (ushort)bf_bits(tile[tx][ty + (k << 3)]);
  }
}

// ---------------- Kernel C: causal Toeplitz filter via MFMA -----------------
// R4 wave structure (wave owns whole chunks K ≡ wave mod 4, all 4 cc) but the
// K-loop is split into 4 PHASES with statically-known active-cc sets, so the
// inner body is branch-free. Boundary overshoot lands in the extended x pad
// (zeros) -> contributes nothing.
template <int P>
__device__ __forceinline__ void chunk_body(int K, const uint* __restrict__ wu,
                                           const uint4* arena16, int ln31, int q,
                                           int s0_par, v16f acc[4][2]) {
  const int ibase = -4 + 8 * K;
  const int s0 = 8303 - 16 * ibase - ln31 + 8 * q;
  const int dw0 = (s0 - s0_par) >> 1;
  uint4 av[10];
  #pragma unroll
  for (int j2 = 0; j2 < 10; ++j2)
    av[j2] = ((const U16*)(wu + (dw0 - 8 * j2)))->v;
  #pragma unroll
  for (int ii = 0; ii < 8; ++ii) {
    const int i = ibase + ii;
    const v8bf A0 = __builtin_bit_cast(v8bf, av[ii]);
    const v8bf A1 = __builtin_bit_cast(v8bf, av[ii + 2]);   // dw-16 reuse
    const int m2 = -2 * (i + 1);
    const int u70 = m2 & 7;
    const int u71 = (m2 + 1) & 7;
    const int G0 = u70 * ROWL + (XPAD / 64) + ((m2 - u70) >> 3);
    const int G1 = u71 * ROWL + (XPAD / 64) + ((m2 + 1 - u71) >> 3);
    const int phi = ln31 + (q ? G1 : G0);
    #pragma unroll
    for (int cc = P; cc < 4; ++cc) {
      const uint4 bv = arena16[phi + 32 * cc];
      const v8bf Bf = __builtin_bit_cast(v8bf, bv);
      acc[cc][0] = __builtin_amdgcn_mfma_f32_32x32x16_bf16(A0, Bf, acc[cc][0], 0, 0, 0);
      acc[cc][1] = __builtin_amdgcn_mfma_f32_32x32x16_bf16(A1, Bf, acc[cc][1], 0, 0, 0);
    }
  }
}

__global__ __launch_bounds__(256, 2) void convk(const ushort* __restrict__ wr2,
                                                const ushort* __restrict__ xT,
                                                float* __restrict__ yT) {
  const int sid = blockIdx.x;
  const int tid = threadIdx.x;
  const int wave = tid >> 6;
  const int lane = tid & 63;
  const int ln31 = lane & 31;
  const int q = lane >> 5;

  __shared__ uint4 arena16[NCHUNK];    // 21 KB; x-stage (main) / reduce zones

  // zero left pad: chunks u in [0, 288)
  for (int u = tid; u < XPAD / 8; u += 256)
    arena16[((u & 7) * ROWL) + (u >> 3)] = make_uint4(0, 0, 0, 0);
  // stage x: data chunk u = 288 + u0, u0 in [0,1024)
  {
    const uint4* xg16 = (const uint4*)(xT + (size_t)sid * T);
    for (int u0 = tid; u0 < 1024; u0 += 256) {
      const int u = u0 + XPAD / 8;
      arena16[((u & 7) * ROWL) + (u >> 3)] = xg16[u0];
    }
  }
  __syncthreads();

  v16f acc[4][2];
  #pragma unroll
  for (int cc = 0; cc < 4; ++cc)
    #pragma unroll
    for (int rt = 0; rt < 2; ++rt)
      #pragma unroll
      for (int e = 0; e < 16; ++e) acc[cc][rt][e] = 0.f;

  const int s0_par = (8303 - ln31 + 8 * q) & 1;
  const uint* wu = (const uint*)(wr2 + (s0_par ? WREV_COPY_STRIDE : 0) +
                                 (size_t)sid * WREV_LEN);

  // phase 0: K in [0,16], cc 0..3 active
  for (int K = wave; K <= 16; K += 4)
    chunk_body<0>(K, wu, arena16, ln31, q, s0_par, acc);
  // phase 1: K in [17,32], cc 1..3
  for (int K = 17 + ((wave + 3) & 3); K <= 32; K += 4)
    chunk_body<1>(K, wu, arena16, ln31, q, s0_par, acc);
  // phase 2: K in [33,48], cc 2..3
  for (int K = 33 + ((wave + 3) & 3); K <= 48; K += 4)
    chunk_body<2>(K, wu, arena16, ln31, q, s0_par, acc);
  // phase 3: K in [49,64], cc 3
  for (int K = 49 + ((wave + 3) & 3); K <= 64; K += 4)
    chunk_body<3>(K, wu, arena16, ln31, q, s0_par, acc);

  // ---- cross-wave reduction of partial D tiles through LDS (R4 scheme) ----
  float* const zbase = (float*)arena16;
  const int rowq = 4 * q;
  #pragma unroll
  for (int cc = 0; cc < 4; ++cc) {
    #pragma unroll
    for (int rt = 0; rt < 2; ++rt) {
      __syncthreads();
      float* zone = zbase + wave * 1152;
      #pragma unroll
      for (int g = 0; g < 4; ++g) {
        float4 v = make_float4(acc[cc][rt][4 * g], acc[cc][rt][4 * g + 1],
                               acc[cc][rt][4 * g + 2], acc[cc][rt][4 * g + 3]);
        *(float4*)(zone + ln31 * 36 + 8 * g + rowq) = v;
      }
      __syncthreads();
      const int n2 = tid & 31, rg = tid >> 5;
      const int zi = n2 * 36 + 4 * rg;
      float4 s0 = *(const float4*)(zbase + 0 * 1152 + zi);
      float4 s1 = *(const float4*)(zbase + 1 * 1152 + zi);
      float4 s2 = *(const float4*)(zbase + 2 * 1152 + zi);
      float4 s3 = *(const float4*)(zbase + 3 * 1152 + zi);
      float4 s;
      s.x = s0.x + s1.x + s2.x + s3.x;
      s.y = s0.y + s1.y + s2.y + s3.y;
      s.z = s0.z + s1.z + s2.z + s3.z;
      s.w = s0.w + s1.w + s2.w + s3.w;
      *(float4*)(yT + (size_t)sid * T + 2048 * cc + 64 * n2 + 32 * rt + 4 * rg) = s;
    }
  }
}

// ---------------- Kernel D: out = Y[:,1:,:] - X[:,:-1,:] @ A^T  (MFMA) ------
__global__ __launch_bounds__(256) void outk(const float* __restrict__ X,
                                            const float* __restrict__ A,
                                            const float* __restrict__ yT,
                                            float* __restrict__ out) {
  const int b = blockIdx.y;
  const int t0 = blockIdx.x << 6;     // 64 t's per block
  const int tid = threadIdx.x;
  const int wave = tid >> 6;          // = n-tile
  const int lane = tid & 63;
  const int ln31 = lane & 31;
  const int q = lane >> 5;

  __shared__ uint4 arena[3072];       // 48KB: Amat 32KB + X 16KB, reused for yT

  // stage Amat bf16: chunk (j, c4) at phiA = c4*128 + ((j + c4) & 127)
  {
    const float* Ab = A + (size_t)b * NCH * NCH;
    #pragma unroll
    for (int g = 0; g < 8; ++g) {
      const int u = g * 256 + tid;
      const int jr = u >> 4, c4 = u & 15;
      const float4 f0 = *(const float4*)(Ab + jr * NCH + 8 * c4);
      const float4 f1 = *(const float4*)(Ab + jr * NCH + 8 * c4 + 4);
      uint4 pk;
      pk.x = bf_bits(f0.x) | (bf_bits(f0.y) << 16);
      pk.y = bf_bits(f0.z) | (bf_bits(f0.w) << 16);
      pk.z = bf_bits(f1.x) | (bf_bits(f1.y) << 16);
      pk.w = bf_bits(f1.z) | (bf_bits(f1.w) << 16);
      arena[c4 * 128 + ((jr + c4) & 127)] = pk;
    }
  }
  // stage X-tile bf16: chunk (m, c4) at 2048 + c4*64 + ((m + c4) & 63)
  {
    const float* Xb = X + ((size_t)b * T + t0) * NCH;
    #pragma unroll
    for (int g = 0; g < 4; ++g) {
      const int u = g * 256 + tid;
      const int m = u >> 4, c4 = u & 15;
      const float4 f0 = *(const float4*)(Xb + m * NCH + 8 * c4);
      const float4 f1 = *(const float4*)(Xb + m * NCH + 8 * c4 + 4);
      uint4 pk;
      pk.x = bf_bits(f0.x) | (bf_bits(f0.y) << 16);
      pk.y = bf_bits(f0.z) | (bf_bits(f0.w) << 16);
      pk.z = bf_bits(f1.x) | (bf_bits(f1.y) << 16);
      pk.w = bf_bits(f1.z) | (bf_bits(f1.w) << 16);
      arena[2048 + c4 * 64 + ((m + c4) & 63)] = pk;
    }
  }
  __syncthreads();

  v16f acc[2];
  #pragma unroll
  for (int mt = 0; mt < 2; ++mt)
    #pragma unroll
    for (int e = 0; e < 16; ++e) acc[mt][e] = 0.f;

  const int nt = wave;
  #pragma unroll
  for (int kk = 0; kk < 8; ++kk) {
    const int c4 = 2 * kk + q;
    const uint4 bv = arena[c4 * 128 + ((nt * 32 + ln31 + c4) & 127)];
    const v8bf Bf = __builtin_bit_cast(v8bf, bv);
    #pragma unroll
    for (int mt = 0; mt < 2; ++mt) {
      const uint4 avv = arena[2048 + c4 * 64 + ((mt * 32 + ln31 + c4) & 63)];
      const v8bf Af = __builtin_bit_cast(v8bf, avv);
      acc[mt] = __builtin_amdgcn_mfma_f32_32x32x16_bf16(Af, Bf, acc[mt], 0, 0, 0);
    }
  }

  __syncthreads();                     // Amat/X dead; reuse arena for yT tile
  // stage yT tile: yl[t][j] = yT[j][t0 + t + 1], rows stride 133 (2-way banks)
  float* const yl = (float*)arena;     // 64*133 = 8512 floats = 34KB
  {
    #pragma unroll
    for (int g = 0; g < 8; ++g) {
      const int u = g * 256 + tid;     // 0..2047
      const int jr = u >> 4, c = u & 15;
      const float* yg = yT + ((size_t)(b * NCH + jr)) * T + t0 + 4 * c + 1;
      const float4 v = ((const F16V*)yg)->v;
      yl[(4 * c + 0) * 133 + jr] = v.x;
      yl[(4 * c + 1) * 133 + jr] = v.y;
      yl[(4 * c + 2) * 133 + jr] = v.z;
      yl[(4 * c + 3) * 133 + jr] = v.w;
    }
  }
  __syncthreads();

  const int jj = nt * 32 + ln31;
  float* og = out + (size_t)b * TM1 * NCH + jj;
  #pragma unroll
  for (int mt = 0; mt < 2; ++mt) {
    #pragma unroll
    for (int g = 0; g < 4; ++g) {
      const int r0 = mt * 32 + 8 * g + 4 * q;          // rows r0..r0+3
      #pragma unroll
      for (int e = 0; e < 4; ++e) {
        const int t = t0 + r0 + e;
        const float val = yl[(r0 + e) * 133 + jj] - acc[mt][4 * g + e];
        if (t < TM1) og[(size_t)t * NCH] = val;
      }
    }
  }
}

extern "C" void kernel_launch(void* const* d_in, const int* in_sizes, int n_in,
                              void* d_out, int out_size, void* d_ws, size_t ws_size,
                              hipStream_t stream) {
  const float* X     = (const float*)d_in[0];   // (8, 8192, 128)
  const float* alpha = (const float*)d_in[1];   // (8, 128)
  const float* A     = (const float*)d_in[2];   // (8, 128, 128)
  float* out = (float*)d_out;                   // (8, 8191, 128)
  char* ws = (char*)d_ws;

  ushort* wr2 = (ushort*)ws;                         // 34,603,008 B
  ushort* xT  = (ushort*)(ws + 34603008);            // 16,777,216 B
  float*  yT  = (float*)(ws + 34603008 + 16777216);  // 33,554,432 B

  hipLaunchKernelGGL(wkern, dim3(NS), dim3(256), 0, stream, alpha, wr2);
  hipLaunchKernelGGL(tkern, dim3(T / 32, NCH / 32, NB), dim3(32, 8), 0, stream, X, xT);
  hipLaunchKernelGGL(convk, dim3(NS), dim3(256), 0, stream, wr2, xT, yT);
  hipLaunchKernelGGL(outk, dim3(T / 64, NB), dim3(256), 0, stream, X, A, yT, out);
}